// Round 4
// baseline (1428.558 us; speedup 1.0000x reference)
//
#include <hip/hip_runtime.h>
#include <stdint.h>

// Baum-Welch forward-backward posteriors (log_gamma), MI355X gfx950.
//
// R7 -> R8: fused fwd+bwd in ONE kernel, shared A-fragment.
//  - Per-step issue was dominated by per-wave fixed overhead x waves/SIMD;
//    fusing both chains amortizes barriers/staging/loop over 2x work.
//  - Lane holds A-block [16 i x 8 j] (128 floats, f2-packed over j).
//    fwd uses it as  sum_i x[i]*A[i][j] (splat-x pk_fma, reduce over i);
//    bwd uses it as  sum_j A[i][j]*w[j] (elementwise pk_fma, reduce over j).
//  - igrp=c&15 -> fwd reduce FULLY in-wave (DPP ^1/^2/^4 + shfl ^8);
//    jgrp=(c>>4)|(g<<2) -> bwd reduce = shfl ^16/^32 + 8-way LDS partial.
//  - No extra global storage: phase 1 (s<255) fwd stores raw alpha rows
//    1..255, bwd raw beta rows 256..510; phase 2 each chain reads partner
//    row (rbuf 8-slot window for s<=258, else gout) and writes the gamma
//    product in place. Split rbufF/rbufB kills slot aliasing.
//  - Full __syncthreads only on flush steps + handoff window [253,272]
//    (global store->load visibility); otherwise lgkm-only barriers.
//  - gamma_norm streaming pass unchanged.

#define NB 256
#define TT 512
#define KK 256
#define VV 4096
#define LOG2E 1.44269504088896f
#define LN2 0.693147180559945f

typedef float f2 __attribute__((ext_vector_type(2)));
typedef float f4 __attribute__((ext_vector_type(4)));

__device__ __forceinline__ void bar_lds() {
  asm volatile("s_waitcnt lgkmcnt(0)" ::: "memory");
  __builtin_amdgcn_s_barrier();
}

// Butterfly add over lane bits 0..3 (16 i-group replicas).
// ^1 = quad_perm(1,0,3,2), ^2 = quad_perm(2,3,0,1),
// ^4 = row_half_mirror(^7) then quad_reverse(^3), ^8 = shfl.
__device__ __forceinline__ float red16(float x) {
  int t;
  t = __builtin_amdgcn_update_dpp(0, __float_as_int(x), 0xB1, 0xF, 0xF, true);
  x += __int_as_float(t);
  t = __builtin_amdgcn_update_dpp(0, __float_as_int(x), 0x4E, 0xF, 0xF, true);
  x += __int_as_float(t);
  t = __builtin_amdgcn_update_dpp(0, __float_as_int(x), 0x141, 0xF, 0xF, true);
  t = __builtin_amdgcn_update_dpp(0, t, 0x1B, 0xF, 0xF, true);
  x += __int_as_float(t);
  x += __shfl_xor(x, 8);
  return x;
}

__global__ __launch_bounds__(512, 2) void hmm_fused(
    const float* __restrict__ lpi, const float* __restrict__ lA,
    const float* __restrict__ lB, const int* __restrict__ obs,
    float* __restrict__ gout) {
  const int n = blockIdx.x;
  const int tid = threadIdx.x;  // 0..511
  const int g = tid >> 6;
  const int c = tid & 63;
  const int igrp = c & 15;              // i in [16*igrp, +16)
  const int jgrp = (c >> 4) | (g << 2); // j in [8*jgrp, +8)
  const int I0 = igrp * 16, J0 = jgrp * 8;
  const bool fstage = (igrp == 0);      // 32 fwd-staging lanes (4 per wave)

  __shared__ int obs_s[TT];                        // 2 KB
  __shared__ __align__(16) float xv[2][KK];        // fwd staged vector
  __shared__ __align__(16) float wv[2][KK];        // bwd staged vector
  __shared__ __align__(16) float rbufF[8][KK];     // fwd row slots (8 KB)
  __shared__ __align__(16) float rbufB[8][KK];     // bwd row slots (8 KB)
  __shared__ __align__(16) float bpart[8][KK];     // bwd cross-wave partials

  for (int i2 = tid; i2 < TT; i2 += 512) obs_s[i2] = obs[n * TT + i2];

  // Shared A fragment: a2[i][jp] = exp(A[I0+i][J0+2jp .. +1]), f2 over j.
  f2 a2[16][4];
#pragma unroll
  for (int i = 0; i < 16; ++i) {
#pragma unroll
    for (int jp = 0; jp < 4; ++jp) {
      f2 p;
      p[0] = exp2f(lA[(size_t)(I0 + i) * KK + J0 + 2 * jp] * LOG2E);
      p[1] = exp2f(lA[(size_t)(I0 + i) * KK + J0 + 2 * jp + 1] * LOG2E);
      a2[i][jp] = p;
    }
  }
  __syncthreads();  // obs_s ready

  const size_t rowbase = (size_t)n * TT * KK;
  // ---- init: alpha row 0, beta row 511, staged vectors ----
  if (tid < KK) {
    const int o0 = obs_s[0], oL = obs_s[TT - 1];
    const float u0 = exp2f((lpi[tid] + lB[(size_t)tid * VV + o0]) * LOG2E);
    xv[0][tid] = u0;
    gout[rowbase + tid] = u0;                               // raw alpha[0]
    wv[0][tid] = exp2f(lB[(size_t)tid * VV + oL] * LOG2E);  // w_{510}
    gout[rowbase + (size_t)(TT - 1) * KK + tid] = 1.0f;     // beta[511] = 1
  }
  __syncthreads();

  // persistent prefetch registers
  float blf[8];
  f4 pfF0 = (f4)0.f, pfF1 = (f4)0.f;
  float blb = 0.f, pfB = 0.f;
  if (fstage) {
    const int o1 = obs_s[1];
#pragma unroll
    for (int k = 0; k < 8; ++k) blf[k] = lB[(size_t)(J0 + k) * VV + o1];
  }
  if (tid < KK) blb = lB[(size_t)tid * VV + obs_s[TT - 2]];

#pragma unroll 1
  for (int s = 0; s < TT - 1; ++s) {
    const int cur = s & 1, nxt = cur ^ 1;
    const bool phase2 = (s >= 255);
    const bool use_rbuf = (s <= 258);

    // ---- dual dot (all lanes) ----
    const f4* xp = (const f4*)&xv[cur][I0];
    const f4 x0 = xp[0], x1 = xp[1], x2 = xp[2], x3 = xp[3];
    const f4* wpv = (const f4*)&wv[cur][J0];
    const f4 wa = wpv[0], wb = wpv[1];
    const float refF = fmaxf(xv[cur][0], 1e-30f);
    const float refB = fmaxf(wv[cur][0], 1e-30f);
    f2 w2[4];
    w2[0][0] = wa[0]; w2[0][1] = wa[1]; w2[1][0] = wa[2]; w2[1][1] = wa[3];
    w2[2][0] = wb[0]; w2[2][1] = wb[1]; w2[3][0] = wb[2]; w2[3][1] = wb[3];

    f2 acc[4];
    acc[0] = (f2)0.f; acc[1] = (f2)0.f; acc[2] = (f2)0.f; acc[3] = (f2)0.f;
    float bacc[16];
#pragma unroll
    for (int i = 0; i < 16; ++i) {
      const float xi = (i < 4) ? x0[i] : (i < 8) ? x1[i - 4]
                       : (i < 12) ? x2[i - 8] : x3[i - 12];
      f2 xs; xs[0] = xi; xs[1] = xi;
      acc[0] += xs * a2[i][0];
      acc[1] += xs * a2[i][1];
      acc[2] += xs * a2[i][2];
      acc[3] += xs * a2[i][3];
      f2 t = a2[i][0] * w2[0];
      t += a2[i][1] * w2[1];
      t += a2[i][2] * w2[2];
      t += a2[i][3] * w2[3];
      bacc[i] = t[0] + t[1];
    }

    // fwd reduce over igrp (lane bits 0..3) -> every lane holds full sums
    float rf[8];
#pragma unroll
    for (int k = 0; k < 8; ++k) rf[k] = red16(acc[k >> 1][k & 1]);

    // bwd reduce over jgrp lane bits (4,5); cross-wave via bpart
#pragma unroll
    for (int i = 0; i < 16; ++i) {
      float v = bacc[i];
      v += __shfl_xor(v, 16);
      v += __shfl_xor(v, 32);
      bacc[i] = v;
    }
    if (c < 16) {  // igrp == c: write partials for i in [16c, 16c+16)
      f4 b0, b1, b2, b3;
      b0[0]=bacc[0];  b0[1]=bacc[1];  b0[2]=bacc[2];  b0[3]=bacc[3];
      b1[0]=bacc[4];  b1[1]=bacc[5];  b1[2]=bacc[6];  b1[3]=bacc[7];
      b2[0]=bacc[8];  b2[1]=bacc[9];  b2[2]=bacc[10]; b2[3]=bacc[11];
      b3[0]=bacc[12]; b3[1]=bacc[13]; b3[2]=bacc[14]; b3[3]=bacc[15];
      f4* bp = (f4*)&bpart[g][16 * c];
      bp[0] = b0; bp[1] = b1; bp[2] = b2; bp[3] = b3;
    }

    // ---- fwd staging (pre-B1) ----
    const int rowF = s + 1;
    if (fstage) {
      const float rF = __builtin_amdgcn_rcpf(refF);
      float u[8];
#pragma unroll
      for (int k = 0; k < 8; ++k) u[k] = rf[k] * rF * exp2f(blf[k] * LOG2E);
      f4 ua, ub;
      ua[0]=u[0]; ua[1]=u[1]; ua[2]=u[2]; ua[3]=u[3];
      ub[0]=u[4]; ub[1]=u[5]; ub[2]=u[6]; ub[3]=u[7];
      *(f4*)&xv[nxt][J0] = ua;
      *(f4*)&xv[nxt][J0 + 4] = ub;
      float* rrow = &rbufF[rowF & 7][J0];
      if (!phase2) {
        *(f4*)rrow = ua; *(f4*)(rrow + 4) = ub;           // raw alpha
      } else {
        f4 b0, b1;
        if (use_rbuf) {
          const float* br = &rbufB[rowF & 7][J0];
          b0 = *(const f4*)br; b1 = *(const f4*)(br + 4);
        } else {
          b0 = pfF0; b1 = pfF1;
        }
        *(f4*)rrow = ua * b0; *(f4*)(rrow + 4) = ub * b1;  // gamma product
      }
      if (s < TT - 2) {
        const int o2 = obs_s[s + 2];
#pragma unroll
        for (int k = 0; k < 8; ++k) blf[k] = lB[(size_t)(J0 + k) * VV + o2];
        if (s >= 258) {  // next step reads beta row s+2 from gout
          const float* gp = &gout[rowbase + (size_t)(s + 2) * KK + J0];
          pfF0 = *(const f4*)gp; pfF1 = *(const f4*)(gp + 4);
        }
      }
    }
    bar_lds();  // B1: bpart + (ordering for rbuf cross-reads)

    // ---- bwd staging (post-B1): tid < 256, i = tid ----
    if (tid < KK) {
      float sb = bpart[0][tid] + bpart[1][tid] + bpart[2][tid] + bpart[3][tid]
               + bpart[4][tid] + bpart[5][tid] + bpart[6][tid] + bpart[7][tid];
      const float beta = sb * __builtin_amdgcn_rcpf(refB);
      wv[nxt][tid] = beta * exp2f(blb * LOG2E);
      const int rowB = TT - 2 - s;  // 510-s
      float* rp = &rbufB[rowB & 7][tid];
      if (!phase2) {
        *rp = beta;                                        // raw beta
      } else {
        const float al = use_rbuf ? rbufF[rowB & 7][tid] : pfB;
        *rp = al * beta;                                   // gamma product
      }
      if (s < TT - 2) {
        blb = lB[(size_t)tid * VV + obs_s[TT - 3 - s]];
        if (s >= 258)  // next step reads alpha row 509-s from gout
          pfB = gout[rowbase + (size_t)(TT - 3 - s) * KK + tid];
      }
    }

    // ---- B2 + flushes ----
    const bool fF = ((s + 1) & 7) == 0;       // s = 7, 15, ..., 503
    const bool fB = ((TT - 2 - s) & 7) == 0;  // s = 6, 14, ..., 510
    if (fF | fB | (s >= 253 && s <= 272)) __syncthreads();
    else bar_lds();
    if (fF) {  // fwd rows s-6 .. s+1
      const int r = s - 6 + (tid >> 6);
      *(f4*)&gout[rowbase + (size_t)r * KK + (tid & 63) * 4] =
          *(const f4*)&rbufF[r & 7][(tid & 63) * 4];
    }
    if (fB) {  // bwd rows (510-s) .. (517-s), skip row 511 at s=6
      const int r = (TT - 2 - s) + (tid >> 6);
      if (r < TT - 1)
        *(f4*)&gout[rowbase + (size_t)r * KK + (tid & 63) * 4] =
            *(const f4*)&rbufB[r & 7][(tid & 63) * 4];
    }
  }

  // tail: fwd product rows 505..511
  __syncthreads();
  if (tid < KK) {
#pragma unroll
    for (int r = TT - 7; r < TT; ++r)
      gout[rowbase + (size_t)r * KK + tid] = rbufF[r & 7][tid];
  }
}

// Pass 3: log-normalize each (n,t) row of 256 positive scaled alpha*beta
// values in place: out = (log2(v) - log2(sum v)) * ln2. Pure streaming.
__global__ __launch_bounds__(256) void gamma_norm(float* __restrict__ gout) {
  const int wave = blockIdx.x * 4 + (threadIdx.x >> 6);
  const int c = threadIdx.x & 63;
  const int stride = gridDim.x * 4;
#pragma unroll 1
  for (int row = wave; row < NB * TT; row += stride) {
    float* p = gout + (size_t)row * KK + c * 4;
    const f4 v = *(const f4*)p;
    float s = (v[0] + v[1]) + (v[2] + v[3]);
#pragma unroll
    for (int d = 1; d < 64; d <<= 1) s += __shfl_xor(s, d);
    const float lg = __log2f(s);
    f4 o;
    o[0] = (__log2f(v[0]) - lg) * LN2;
    o[1] = (__log2f(v[1]) - lg) * LN2;
    o[2] = (__log2f(v[2]) - lg) * LN2;
    o[3] = (__log2f(v[3]) - lg) * LN2;
    *(f4*)p = o;
  }
}

extern "C" void kernel_launch(void* const* d_in, const int* in_sizes, int n_in,
                              void* d_out, int out_size, void* d_ws, size_t ws_size,
                              hipStream_t stream) {
  const float* lpi = (const float*)d_in[0];
  const float* lA = (const float*)d_in[1];
  const float* lB = (const float*)d_in[2];
  const int* obs = (const int*)d_in[3];
  float* gout = (float*)d_out;
  (void)d_ws; (void)ws_size;  // deliberately unused

  hmm_fused<<<NB, 512, 0, stream>>>(lpi, lA, lB, obs, gout);
  gamma_norm<<<2048, 256, 0, stream>>>(gout);
}